// Round 1
// baseline (264.111 us; speedup 1.0000x reference)
//
#include <hip/hip_runtime.h>
#include <cstddef>

#define IMG 256
#define HW 65536
#define NB 4
#define NC_IN 48
#define NHEADS 8
#define TILE 14
#define HALO 16
#define NT 19          // ceil(256/14)
#define NTILES (NT*NT) // 361

__device__ __forceinline__ unsigned short f2bf(float f) {
    unsigned int x = __float_as_uint(f);
    unsigned int r = (x + 0x7fffu + ((x >> 16) & 1u)) >> 16;
    return (unsigned short)r;
}

__device__ __forceinline__ float waveReduceSum(float v) {
#pragma unroll
    for (int s = 1; s < 64; s <<= 1) v += __shfl_xor(v, s, 64);
    return v;
}

// ---------------------------------------------------------------------------
// K1: q,k = dwconv3x3(conv1x1(fea0, qk_w), qk_dw)  -> bf16 qk_buf[b][96][hw]
// tile: 16x16 halo, 14x14 interior. 8 chunks of 12 oc (head h: q=h*6.., k=48+h*6..)
// ---------------------------------------------------------------------------
__global__ __launch_bounds__(256) void conv_qk_kernel(
    const float* __restrict__ fea0, const float* __restrict__ qk_w,
    const float* __restrict__ qk_dw, unsigned short* __restrict__ qk_buf) {
    __shared__ float t[12][HALO * HALO];
    const int tid = threadIdx.x;
    const int b = blockIdx.y;
    const int tileIdx = blockIdx.x;
    const int tx = tileIdx % NT, ty = tileIdx / NT;

    const int hx = tid & 15, hy = tid >> 4;
    const int gx = tx * TILE + hx - 1, gy = ty * TILE + hy - 1;
    const bool inb = ((unsigned)gx < (unsigned)IMG) && ((unsigned)gy < (unsigned)IMG);
    const int pix = gy * IMG + gx;
    const float* fb = fea0 + (size_t)b * NC_IN * HW;

    float in[NC_IN];
#pragma unroll
    for (int ic = 0; ic < NC_IN; ++ic)
        in[ic] = inb ? fb[(size_t)ic * HW + pix] : 0.f;

    const int ilx = tid % TILE, ily = tid / TILE;
    const int gxi = tx * TILE + ilx, gyi = ty * TILE + ily;
    const bool valid = (tid < TILE * TILE) && (gxi < IMG) && (gyi < IMG);
    const int opix = gyi * IMG + gxi;

    for (int h = 0; h < NHEADS; ++h) {
        float acc[12];
#pragma unroll
        for (int j = 0; j < 12; ++j) acc[j] = 0.f;
#pragma unroll
        for (int ic = 0; ic < NC_IN; ++ic) {
            const float x = in[ic];
#pragma unroll
            for (int j = 0; j < 6; ++j)
                acc[j] = fmaf(qk_w[(h * 6 + j) * NC_IN + ic], x, acc[j]);
#pragma unroll
            for (int j = 0; j < 6; ++j)
                acc[6 + j] = fmaf(qk_w[(48 + h * 6 + j) * NC_IN + ic], x, acc[6 + j]);
        }
        __syncthreads();  // protect previous chunk's LDS reads
#pragma unroll
        for (int j = 0; j < 12; ++j) t[j][tid] = acc[j];
        __syncthreads();
        if (valid) {
            float q[6], k[6];
#pragma unroll
            for (int j = 0; j < 6; ++j) { q[j] = 0.f; k[j] = 0.f; }
#pragma unroll
            for (int dy = 0; dy < 3; ++dy)
#pragma unroll
                for (int dx = 0; dx < 3; ++dx) {
                    const int hp = (ily + dy) * HALO + (ilx + dx);
#pragma unroll
                    for (int j = 0; j < 6; ++j) {
                        q[j] = fmaf(qk_dw[(h * 6 + j) * 9 + dy * 3 + dx], t[j][hp], q[j]);
                        k[j] = fmaf(qk_dw[(48 + h * 6 + j) * 9 + dy * 3 + dx], t[6 + j][hp], k[j]);
                    }
                }
#pragma unroll
            for (int j = 0; j < 6; ++j) {
                qk_buf[((size_t)b * 96 + h * 6 + j) * HW + opix] = f2bf(q[j]);
                qk_buf[((size_t)b * 96 + 48 + h * 6 + j) * HW + opix] = f2bf(k[j]);
            }
        }
    }
}

// ---------------------------------------------------------------------------
// K2: v = dwconv3x3(conv1x1(fea1, v_w), v_dw) -> f32 v_buf[b][48][hw]
// ---------------------------------------------------------------------------
__global__ __launch_bounds__(256) void conv_v_kernel(
    const float* __restrict__ fea1, const float* __restrict__ v_w,
    const float* __restrict__ v_dw, float* __restrict__ v_buf) {
    __shared__ float t[12][HALO * HALO];
    const int tid = threadIdx.x;
    const int b = blockIdx.y;
    const int tileIdx = blockIdx.x;
    const int tx = tileIdx % NT, ty = tileIdx / NT;

    const int hx = tid & 15, hy = tid >> 4;
    const int gx = tx * TILE + hx - 1, gy = ty * TILE + hy - 1;
    const bool inb = ((unsigned)gx < (unsigned)IMG) && ((unsigned)gy < (unsigned)IMG);
    const int pix = gy * IMG + gx;
    const float* fb = fea1 + (size_t)b * NC_IN * HW;

    float in[NC_IN];
#pragma unroll
    for (int ic = 0; ic < NC_IN; ++ic)
        in[ic] = inb ? fb[(size_t)ic * HW + pix] : 0.f;

    const int ilx = tid % TILE, ily = tid / TILE;
    const int gxi = tx * TILE + ilx, gyi = ty * TILE + ily;
    const bool valid = (tid < TILE * TILE) && (gxi < IMG) && (gyi < IMG);
    const int opix = gyi * IMG + gxi;

    for (int ch = 0; ch < 4; ++ch) {  // 4 chunks of 12 oc
        float acc[12];
#pragma unroll
        for (int j = 0; j < 12; ++j) acc[j] = 0.f;
#pragma unroll
        for (int ic = 0; ic < NC_IN; ++ic) {
            const float x = in[ic];
#pragma unroll
            for (int j = 0; j < 12; ++j)
                acc[j] = fmaf(v_w[(ch * 12 + j) * NC_IN + ic], x, acc[j]);
        }
        __syncthreads();
#pragma unroll
        for (int j = 0; j < 12; ++j) t[j][tid] = acc[j];
        __syncthreads();
        if (valid) {
            float o[12];
#pragma unroll
            for (int j = 0; j < 12; ++j) o[j] = 0.f;
#pragma unroll
            for (int dy = 0; dy < 3; ++dy)
#pragma unroll
                for (int dx = 0; dx < 3; ++dx) {
                    const int hp = (ily + dy) * HALO + (ilx + dx);
#pragma unroll
                    for (int j = 0; j < 12; ++j)
                        o[j] = fmaf(v_dw[(ch * 12 + j) * 9 + dy * 3 + dx], t[j][hp], o[j]);
                }
#pragma unroll
            for (int j = 0; j < 12; ++j)
                v_buf[((size_t)b * NC_IN + ch * 12 + j) * HW + opix] = o[j];
        }
    }
}

// ---------------------------------------------------------------------------
// K3: per (b,h): qq[6], kk[6], qk[6][6] reductions over 65536 pixels
// stats layout per b (384 f32): [0..47]=qq(c), [48..95]=kk(c), [96..]=h*36+cc*6+d
// ---------------------------------------------------------------------------
__global__ __launch_bounds__(256) void stats_kernel(
    const unsigned short* __restrict__ qk_buf, float* __restrict__ stats) {
    const int tid = threadIdx.x;
    const int b = blockIdx.z, h = blockIdx.y;
    const unsigned short* qb = qk_buf + ((size_t)b * 96 + h * 6) * HW;
    const unsigned short* kb = qk_buf + ((size_t)b * 96 + 48 + h * 6) * HW;

    float aqq[6] = {0, 0, 0, 0, 0, 0}, akk[6] = {0, 0, 0, 0, 0, 0}, aqk[36];
#pragma unroll
    for (int i = 0; i < 36; ++i) aqk[i] = 0.f;

    for (int p = blockIdx.x * 256 + tid; p < HW / 2; p += 16 * 256) {
        const int p2 = p * 2;
        float qx[6], qy[6], kx[6], ky[6];
#pragma unroll
        for (int j = 0; j < 6; ++j) {
            const unsigned int uq = *(const unsigned int*)&qb[(size_t)j * HW + p2];
            const unsigned int uk = *(const unsigned int*)&kb[(size_t)j * HW + p2];
            qx[j] = __uint_as_float(uq << 16);
            qy[j] = __uint_as_float(uq & 0xffff0000u);
            kx[j] = __uint_as_float(uk << 16);
            ky[j] = __uint_as_float(uk & 0xffff0000u);
        }
#pragma unroll
        for (int j = 0; j < 6; ++j) {
            aqq[j] += qx[j] * qx[j] + qy[j] * qy[j];
            akk[j] += kx[j] * kx[j] + ky[j] * ky[j];
        }
#pragma unroll
        for (int cc = 0; cc < 6; ++cc)
#pragma unroll
            for (int d = 0; d < 6; ++d)
                aqk[cc * 6 + d] += qx[cc] * kx[d] + qy[cc] * ky[d];
    }

    const int lane = tid & 63;
    float* sb = stats + b * 384;
#pragma unroll
    for (int j = 0; j < 6; ++j) {
        float r = waveReduceSum(aqq[j]);
        if (lane == 0) atomicAdd(&sb[h * 6 + j], r);
        r = waveReduceSum(akk[j]);
        if (lane == 0) atomicAdd(&sb[48 + h * 6 + j], r);
    }
#pragma unroll
    for (int i = 0; i < 36; ++i) {
        float r = waveReduceSum(aqk[i]);
        if (lane == 0) atomicAdd(&sb[96 + h * 36 + i], r);
    }
}

// ---------------------------------------------------------------------------
// K4: softmax over 6 + fold proj: W2[b][c][dg] = sum_cc proj_w[c][h*6+cc]*attn[h][cc][hd]
// ---------------------------------------------------------------------------
__global__ __launch_bounds__(256) void softmax_w2_kernel(
    const float* __restrict__ stats, const float* __restrict__ proj_w,
    const float* __restrict__ temperature, float* __restrict__ w2) {
    const int b = blockIdx.x;
    const int tid = threadIdx.x;
    __shared__ float attn[NHEADS * 36];
    const float* sb = stats + b * 384;

    if (tid < 48) {
        const int h = tid / 6, cc = tid % 6;
        float nq = fmaxf(sqrtf(sb[tid]), 1e-12f);
        const float tmp = temperature[h];
        float lo[6];
#pragma unroll
        for (int d = 0; d < 6; ++d) {
            const float nk = fmaxf(sqrtf(sb[48 + h * 6 + d]), 1e-12f);
            lo[d] = sb[96 + h * 36 + cc * 6 + d] / (nq * nk) * tmp;
        }
        float m = lo[0];
#pragma unroll
        for (int d = 1; d < 6; ++d) m = fmaxf(m, lo[d]);
        float s = 0.f;
#pragma unroll
        for (int d = 0; d < 6; ++d) { lo[d] = expf(lo[d] - m); s += lo[d]; }
        const float inv = 1.f / s;
#pragma unroll
        for (int d = 0; d < 6; ++d) attn[h * 36 + cc * 6 + d] = lo[d] * inv;
    }
    __syncthreads();

    for (int idx = tid; idx < 48 * 48; idx += 256) {
        const int c = idx / 48, dg = idx % 48;
        const int h = dg / 6, hd = dg % 6;
        float s = 0.f;
#pragma unroll
        for (int cc = 0; cc < 6; ++cc)
            s = fmaf(proj_w[c * 48 + h * 6 + cc], attn[h * 36 + cc * 6 + hd], s);
        w2[b * 2304 + idx] = s;
    }
}

// ---------------------------------------------------------------------------
// K5: out[b][c][pix] = sum_d W2[b][c][d] * v[b][d][pix]   (2 px / thread)
// ---------------------------------------------------------------------------
__global__ __launch_bounds__(256) void out_kernel(
    const float* __restrict__ v_buf, const float* __restrict__ w2,
    float* __restrict__ out) {
    __shared__ float w[48 * 48];
    const int b = blockIdx.y;
    for (int i = threadIdx.x; i < 48 * 48; i += 256) w[i] = w2[b * 2304 + i];
    __syncthreads();

    const int pixBase = (blockIdx.x * 256 + threadIdx.x) * 2;
    const float* vb = v_buf + (size_t)b * 48 * HW;
    float* ob = out + (size_t)b * 48 * HW;

    float vx[48], vy[48];
#pragma unroll
    for (int d = 0; d < 48; ++d) {
        const float2 t = *reinterpret_cast<const float2*>(&vb[(size_t)d * HW + pixBase]);
        vx[d] = t.x; vy[d] = t.y;
    }
#pragma unroll
    for (int c = 0; c < 48; ++c) {
        float ax = 0.f, ay = 0.f;
#pragma unroll
        for (int d4 = 0; d4 < 12; ++d4) {
            const float4 ww = *reinterpret_cast<const float4*>(&w[c * 48 + d4 * 4]);
            ax = fmaf(ww.x, vx[d4 * 4 + 0], ax); ay = fmaf(ww.x, vy[d4 * 4 + 0], ay);
            ax = fmaf(ww.y, vx[d4 * 4 + 1], ax); ay = fmaf(ww.y, vy[d4 * 4 + 1], ay);
            ax = fmaf(ww.z, vx[d4 * 4 + 2], ax); ay = fmaf(ww.z, vy[d4 * 4 + 2], ay);
            ax = fmaf(ww.w, vx[d4 * 4 + 3], ax); ay = fmaf(ww.w, vy[d4 * 4 + 3], ay);
        }
        float2 r; r.x = ax; r.y = ay;
        *reinterpret_cast<float2*>(&ob[(size_t)c * HW + pixBase]) = r;
    }
}

// ---------------------------------------------------------------------------
extern "C" void kernel_launch(void* const* d_in, const int* in_sizes, int n_in,
                              void* d_out, int out_size, void* d_ws, size_t ws_size,
                              hipStream_t stream) {
    const float* fea0 = (const float*)d_in[0];
    const float* fea1 = (const float*)d_in[1];
    const float* qk_w = (const float*)d_in[2];
    const float* qk_dw = (const float*)d_in[3];
    const float* v_w = (const float*)d_in[4];
    const float* v_dw = (const float*)d_in[5];
    const float* proj_w = (const float*)d_in[6];
    const float* temperature = (const float*)d_in[7];
    float* out = (float*)d_out;

    char* ws = (char*)d_ws;
    const size_t QK_BYTES = (size_t)NB * 96 * HW * sizeof(unsigned short);  // 50,331,648
    const size_t V_BYTES = (size_t)NB * 48 * HW * sizeof(float);            // 50,331,648
    const size_t ST_BYTES = (size_t)NB * 384 * sizeof(float);               // 6,144
    unsigned short* qk_buf = (unsigned short*)ws;
    float* v_buf = (float*)(ws + QK_BYTES);
    float* stats = (float*)(ws + QK_BYTES + V_BYTES);
    float* w2 = (float*)(ws + QK_BYTES + V_BYTES + ST_BYTES);

    hipMemsetAsync(stats, 0, ST_BYTES, stream);

    conv_qk_kernel<<<dim3(NTILES, NB), 256, 0, stream>>>(fea0, qk_w, qk_dw, qk_buf);
    conv_v_kernel<<<dim3(NTILES, NB), 256, 0, stream>>>(fea1, v_w, v_dw, v_buf);
    stats_kernel<<<dim3(16, NHEADS, NB), 256, 0, stream>>>(qk_buf, stats);
    softmax_w2_kernel<<<NB, 256, 0, stream>>>(stats, proj_w, temperature, w2);
    out_kernel<<<dim3(HW / 512, NB), 256, 0, stream>>>(v_buf, w2, out);
}

// Round 2
// 173.091 us; speedup vs baseline: 1.5258x; 1.5258x over previous
//
#include <hip/hip_runtime.h>
#include <cstddef>

#define IMG 256
#define HW 65536
#define NB 4
#define NC_IN 48
#define NHEADS 8
#define TILE 14
#define HALO 16
#define NT 19          // ceil(256/14)
#define NTILES (NT*NT) // 361

typedef short bf16x8 __attribute__((ext_vector_type(8)));
typedef float f32x4 __attribute__((ext_vector_type(4)));
typedef float f32x16 __attribute__((ext_vector_type(16)));

__device__ __forceinline__ unsigned short f2bf(float f) {
    unsigned int x = __float_as_uint(f);
    unsigned int r = (x + 0x7fffu + ((x >> 16) & 1u)) >> 16;
    return (unsigned short)r;
}

// ---------------------------------------------------------------------------
// K1: fused qk path. Per block: 16x16 halo tile (14x14 interior).
//   conv1x1 via MFMA 32x32x16 bf16, M padded to 128 rows (16/head: q6 k6 pad4)
//   -> y LDS -> dwconv3x3 (VALU) -> Gram stats via 16x16x32 MFMA -> atomics.
// No q/k ever written to global.
// stats layout per b (384 f32): [0..47]=qq(h*6+c), [48..95]=kk, [96..]=h*36+cc*6+d
// ---------------------------------------------------------------------------
__global__ __launch_bounds__(256) void fused_qk_stats_kernel(
    const float* __restrict__ fea0, const float* __restrict__ qk_w,
    const float* __restrict__ qk_dw, float* __restrict__ stats) {
    __shared__ float y[256][28];                          // [halo px][24 ch + pad]
    __shared__ __align__(16) unsigned short sg[4][28][72]; // per-wave Gram staging
    __shared__ float sacc[384];

    const int tid = threadIdx.x;
    const int b = blockIdx.y;
    const int tx = blockIdx.x % NT, ty = blockIdx.x / NT;
    const int wave = tid >> 6, lane = tid & 63;
    const int l31 = lane & 31, lhi = lane >> 5;

    for (int i = tid; i < 384; i += 256) sacc[i] = 0.f;

    const float* fb = fea0 + (size_t)b * NC_IN * HW;

    // ---- B fragments: input pixels, held in registers for all m-tiles ----
    bf16x8 Bf[2][3];
#pragma unroll
    for (int n = 0; n < 2; ++n) {
        const int px = wave * 64 + n * 32 + l31;
        const int hx = px & 15, hy = px >> 4;
        const int gx = tx * TILE + hx - 1, gy = ty * TILE + hy - 1;
        const bool inb = ((unsigned)gx < (unsigned)IMG) && ((unsigned)gy < (unsigned)IMG);
        const int pix = inb ? (gy * IMG + gx) : 0;
#pragma unroll
        for (int ks = 0; ks < 3; ++ks) {
            const int ch0 = ks * 16 + lhi * 8;
            float xv[8];
#pragma unroll
            for (int j = 0; j < 8; ++j)
                xv[j] = inb ? fb[(size_t)(ch0 + j) * HW + pix] : 0.f;
            bf16x8 t;
#pragma unroll
            for (int j = 0; j < 8; ++j) t[j] = (short)f2bf(xv[j]);
            Bf[n][ks] = t;
        }
    }

    // interior pixel for dwconv
    const int ilx = tid % TILE, ily = tid / TILE;
    const int gxi = tx * TILE + ilx, gyi = ty * TILE + ily;
    const bool valid = (tid < TILE * TILE) && (gxi < IMG) && (gyi < IMG);

    for (int m = 0; m < 4; ++m) {
        const int h0 = 2 * m, h1 = 2 * m + 1;

        // ---- A fragments: permuted+padded weight rows (per-lane gather) ----
        const int sub = l31 & 15;
        const int hh_ = h0 + (l31 >> 4);
        const bool wok = sub < 12;
        const int wr = (sub < 6) ? (hh_ * 6 + sub) : (48 + hh_ * 6 + (sub - 6));
        bf16x8 Af[3];
#pragma unroll
        for (int ks = 0; ks < 3; ++ks) {
            const int k0 = ks * 16 + lhi * 8;
            float xv[8];
            if (wok) {
                const float4 wa = *(const float4*)&qk_w[wr * 48 + k0];
                const float4 wb = *(const float4*)&qk_w[wr * 48 + k0 + 4];
                xv[0] = wa.x; xv[1] = wa.y; xv[2] = wa.z; xv[3] = wa.w;
                xv[4] = wb.x; xv[5] = wb.y; xv[6] = wb.z; xv[7] = wb.w;
            } else {
#pragma unroll
                for (int j = 0; j < 8; ++j) xv[j] = 0.f;
            }
            bf16x8 t;
#pragma unroll
            for (int j = 0; j < 8; ++j) t[j] = (short)f2bf(xv[j]);
            Af[ks] = t;
        }

        // ---- GEMM: 2 heads x (q6,k6) over this wave's 64 pixels ----
        f32x16 C0, C1;
#pragma unroll
        for (int r = 0; r < 16; ++r) { C0[r] = 0.f; C1[r] = 0.f; }
#pragma unroll
        for (int ks = 0; ks < 3; ++ks) {
            C0 = __builtin_amdgcn_mfma_f32_32x32x16_bf16(Af[ks], Bf[0][ks], C0, 0, 0, 0);
            C1 = __builtin_amdgcn_mfma_f32_32x32x16_bf16(Af[ks], Bf[1][ks], C1, 0, 0, 0);
        }

        __syncthreads();   // previous m-tile's y reads complete
        // C layout (32x32): col=lane&31 (px), row=(r&3)+8*(r>>2)+4*(lane>>5) (ch)
#pragma unroll
        for (int r = 0; r < 16; ++r) {
            const int row = (r & 3) + 8 * (r >> 2) + 4 * lhi;
            const int rsub = row & 15;
            if (rsub < 12) {
                const int ych = (row >> 4) * 12 + rsub;   // 0..23
                y[wave * 64 + l31][ych] = C0[r];
                y[wave * 64 + 32 + l31][ych] = C1[r];
            }
        }
        __syncthreads();

        // ---- depthwise 3x3 on 24 real channels (2 heads) ----
        float qk2[24];
#pragma unroll
        for (int c = 0; c < 24; ++c) qk2[c] = 0.f;
        if (valid) {
#pragma unroll
            for (int dy = 0; dy < 3; ++dy)
#pragma unroll
                for (int dx = 0; dx < 3; ++dx) {
                    const int tap = dy * 3 + dx;
                    const float* yp = &y[(ily + dy) * HALO + (ilx + dx)][0];
                    float yv[24];
                    *(float4*)&yv[0]  = *(const float4*)(yp);
                    *(float4*)&yv[4]  = *(const float4*)(yp + 4);
                    *(float4*)&yv[8]  = *(const float4*)(yp + 8);
                    *(float4*)&yv[12] = *(const float4*)(yp + 12);
                    *(float4*)&yv[16] = *(const float4*)(yp + 16);
                    *(float4*)&yv[20] = *(const float4*)(yp + 20);
#pragma unroll
                    for (int c = 0; c < 24; ++c) {
                        const int hh = (c < 12) ? h0 : h1;
                        const int s = (c < 12) ? c : (c - 12);
                        const int dr = (s < 6) ? (hh * 6 + s) : (48 + hh * 6 + (s - 6));
                        qk2[c] = fmaf(qk_dw[dr * 9 + tap], yv[c], qk2[c]);
                    }
                }
        }

        // ---- Gram stats via MFMA: stage [24ch x 64px] bf16 per wave ----
#pragma unroll
        for (int c = 0; c < 24; ++c) sg[wave][c][lane] = f2bf(qk2[c]);
        asm volatile("s_waitcnt lgkmcnt(0)" ::: "memory");
        __builtin_amdgcn_sched_barrier(0);
        const int fr = lane & 15, fg = lane >> 4;
#pragma unroll
        for (int hh = 0; hh < 2; ++hh) {
            const bf16x8 a0 = *(const bf16x8*)&sg[wave][hh * 12 + fr][fg * 8];
            const bf16x8 a1 = *(const bf16x8*)&sg[wave][hh * 12 + fr][32 + fg * 8];
            f32x4 c4 = {0.f, 0.f, 0.f, 0.f};
            c4 = __builtin_amdgcn_mfma_f32_16x16x32_bf16(a0, a0, c4, 0, 0, 0);
            c4 = __builtin_amdgcn_mfma_f32_16x16x32_bf16(a1, a1, c4, 0, 0, 0);
            const int h = 2 * m + hh;
            // C (16x16): col=lane&15, row=(lane>>4)*4+r ; symmetric matrix
#pragma unroll
            for (int r = 0; r < 4; ++r) {
                const int crow = fg * 4 + r;
                const float vv = c4[r];
                if (crow < 6) {
                    if (fr == crow) atomicAdd(&sacc[h * 6 + crow], vv);
                    else if (fr >= 6 && fr < 12)
                        atomicAdd(&sacc[96 + h * 36 + crow * 6 + (fr - 6)], vv);
                } else if (crow < 12 && fr == crow) {
                    atomicAdd(&sacc[48 + h * 6 + (crow - 6)], vv);
                }
            }
        }
    }

    __syncthreads();
    for (int i = tid; i < 384; i += 256) atomicAdd(&stats[b * 384 + i], sacc[i]);
}

// ---------------------------------------------------------------------------
// K2: fused v path: conv1x1 (MFMA, M=48 padded to 64) -> y LDS -> dwconv ->
// v_buf f32
// ---------------------------------------------------------------------------
__global__ __launch_bounds__(256) void fused_v_kernel(
    const float* __restrict__ fea1, const float* __restrict__ v_w,
    const float* __restrict__ v_dw, float* __restrict__ v_buf) {
    __shared__ float y[256][36];   // [halo px][32 ch + pad]

    const int tid = threadIdx.x;
    const int b = blockIdx.y;
    const int tx = blockIdx.x % NT, ty = blockIdx.x / NT;
    const int wave = tid >> 6, lane = tid & 63;
    const int l31 = lane & 31, lhi = lane >> 5;

    const float* fb = fea1 + (size_t)b * NC_IN * HW;

    bf16x8 Bf[2][3];
#pragma unroll
    for (int n = 0; n < 2; ++n) {
        const int px = wave * 64 + n * 32 + l31;
        const int hx = px & 15, hy = px >> 4;
        const int gx = tx * TILE + hx - 1, gy = ty * TILE + hy - 1;
        const bool inb = ((unsigned)gx < (unsigned)IMG) && ((unsigned)gy < (unsigned)IMG);
        const int pix = inb ? (gy * IMG + gx) : 0;
#pragma unroll
        for (int ks = 0; ks < 3; ++ks) {
            const int ch0 = ks * 16 + lhi * 8;
            float xv[8];
#pragma unroll
            for (int j = 0; j < 8; ++j)
                xv[j] = inb ? fb[(size_t)(ch0 + j) * HW + pix] : 0.f;
            bf16x8 t;
#pragma unroll
            for (int j = 0; j < 8; ++j) t[j] = (short)f2bf(xv[j]);
            Bf[n][ks] = t;
        }
    }

    const int ilx = tid % TILE, ily = tid / TILE;
    const int gxi = tx * TILE + ilx, gyi = ty * TILE + ily;
    const bool valid = (tid < TILE * TILE) && (gxi < IMG) && (gyi < IMG);
    const int opix = gyi * IMG + gxi;

    for (int m = 0; m < 2; ++m) {
        const int grow = m * 32 + l31;
        const bool wok = grow < 48;
        bf16x8 Af[3];
#pragma unroll
        for (int ks = 0; ks < 3; ++ks) {
            const int k0 = ks * 16 + lhi * 8;
            float xv[8];
            if (wok) {
                const float4 wa = *(const float4*)&v_w[grow * 48 + k0];
                const float4 wb = *(const float4*)&v_w[grow * 48 + k0 + 4];
                xv[0] = wa.x; xv[1] = wa.y; xv[2] = wa.z; xv[3] = wa.w;
                xv[4] = wb.x; xv[5] = wb.y; xv[6] = wb.z; xv[7] = wb.w;
            } else {
#pragma unroll
                for (int j = 0; j < 8; ++j) xv[j] = 0.f;
            }
            bf16x8 t;
#pragma unroll
            for (int j = 0; j < 8; ++j) t[j] = (short)f2bf(xv[j]);
            Af[ks] = t;
        }

        f32x16 C0, C1;
#pragma unroll
        for (int r = 0; r < 16; ++r) { C0[r] = 0.f; C1[r] = 0.f; }
#pragma unroll
        for (int ks = 0; ks < 3; ++ks) {
            C0 = __builtin_amdgcn_mfma_f32_32x32x16_bf16(Af[ks], Bf[0][ks], C0, 0, 0, 0);
            C1 = __builtin_amdgcn_mfma_f32_32x32x16_bf16(Af[ks], Bf[1][ks], C1, 0, 0, 0);
        }

        __syncthreads();
#pragma unroll
        for (int r = 0; r < 16; ++r) {
            const int row = (r & 3) + 8 * (r >> 2) + 4 * lhi;
            y[wave * 64 + l31][row] = C0[r];
            y[wave * 64 + 32 + l31][row] = C1[r];
        }
        __syncthreads();

        if (valid) {
            const int nc = m ? 16 : 32;
            float o[32];
#pragma unroll
            for (int c = 0; c < 32; ++c) o[c] = 0.f;
#pragma unroll
            for (int dy = 0; dy < 3; ++dy)
#pragma unroll
                for (int dx = 0; dx < 3; ++dx) {
                    const int tap = dy * 3 + dx;
                    const float* yp = &y[(ily + dy) * HALO + (ilx + dx)][0];
                    float yv[32];
                    *(float4*)&yv[0]  = *(const float4*)(yp);
                    *(float4*)&yv[4]  = *(const float4*)(yp + 4);
                    *(float4*)&yv[8]  = *(const float4*)(yp + 8);
                    *(float4*)&yv[12] = *(const float4*)(yp + 12);
                    *(float4*)&yv[16] = *(const float4*)(yp + 16);
                    *(float4*)&yv[20] = *(const float4*)(yp + 20);
                    *(float4*)&yv[24] = *(const float4*)(yp + 24);
                    *(float4*)&yv[28] = *(const float4*)(yp + 28);
#pragma unroll
                    for (int c = 0; c < 32; ++c) {
                        if (c < nc)
                            o[c] = fmaf(v_dw[(m * 32 + c) * 9 + tap], yv[c], o[c]);
                    }
                }
#pragma unroll
            for (int c = 0; c < 32; ++c) {
                if (c < nc)
                    v_buf[((size_t)b * NC_IN + m * 32 + c) * HW + opix] = o[c];
            }
        }
    }
}

// ---------------------------------------------------------------------------
// K3: softmax over 6 + fold proj: W2[b][c][dg]
// ---------------------------------------------------------------------------
__global__ __launch_bounds__(256) void softmax_w2_kernel(
    const float* __restrict__ stats, const float* __restrict__ proj_w,
    const float* __restrict__ temperature, float* __restrict__ w2) {
    const int b = blockIdx.x;
    const int tid = threadIdx.x;
    __shared__ float attn[NHEADS * 36];
    const float* sb = stats + b * 384;

    if (tid < 48) {
        const int h = tid / 6, cc = tid % 6;
        float nq = fmaxf(sqrtf(sb[tid]), 1e-12f);
        const float tmp = temperature[h];
        float lo[6];
#pragma unroll
        for (int d = 0; d < 6; ++d) {
            const float nk = fmaxf(sqrtf(sb[48 + h * 6 + d]), 1e-12f);
            lo[d] = sb[96 + h * 36 + cc * 6 + d] / (nq * nk) * tmp;
        }
        float m = lo[0];
#pragma unroll
        for (int d = 1; d < 6; ++d) m = fmaxf(m, lo[d]);
        float s = 0.f;
#pragma unroll
        for (int d = 0; d < 6; ++d) { lo[d] = expf(lo[d] - m); s += lo[d]; }
        const float inv = 1.f / s;
#pragma unroll
        for (int d = 0; d < 6; ++d) attn[h * 36 + cc * 6 + d] = lo[d] * inv;
    }
    __syncthreads();

    for (int idx = tid; idx < 48 * 48; idx += 256) {
        const int c = idx / 48, dg = idx % 48;
        const int h = dg / 6, hd = dg % 6;
        float s = 0.f;
#pragma unroll
        for (int cc = 0; cc < 6; ++cc)
            s = fmaf(proj_w[c * 48 + h * 6 + cc], attn[h * 36 + cc * 6 + hd], s);
        w2[b * 2304 + idx] = s;
    }
}

// ---------------------------------------------------------------------------
// K4: out[b][c][pix] = sum_d W2[b][c][d] * v[b][d][pix]   (2 px / thread)
// ---------------------------------------------------------------------------
__global__ __launch_bounds__(256) void out_kernel(
    const float* __restrict__ v_buf, const float* __restrict__ w2,
    float* __restrict__ out) {
    __shared__ float w[48 * 48];
    const int b = blockIdx.y;
    for (int i = threadIdx.x; i < 48 * 48; i += 256) w[i] = w2[b * 2304 + i];
    __syncthreads();

    const int pixBase = (blockIdx.x * 256 + threadIdx.x) * 2;
    const float* vb = v_buf + (size_t)b * 48 * HW;
    float* ob = out + (size_t)b * 48 * HW;

    float vx[48], vy[48];
#pragma unroll
    for (int d = 0; d < 48; ++d) {
        const float2 t = *reinterpret_cast<const float2*>(&vb[(size_t)d * HW + pixBase]);
        vx[d] = t.x; vy[d] = t.y;
    }
#pragma unroll
    for (int c = 0; c < 48; ++c) {
        float ax = 0.f, ay = 0.f;
#pragma unroll
        for (int d4 = 0; d4 < 12; ++d4) {
            const float4 ww = *reinterpret_cast<const float4*>(&w[c * 48 + d4 * 4]);
            ax = fmaf(ww.x, vx[d4 * 4 + 0], ax); ay = fmaf(ww.x, vy[d4 * 4 + 0], ay);
            ax = fmaf(ww.y, vx[d4 * 4 + 1], ax); ay = fmaf(ww.y, vy[d4 * 4 + 1], ay);
            ax = fmaf(ww.z, vx[d4 * 4 + 2], ax); ay = fmaf(ww.z, vy[d4 * 4 + 2], ay);
            ax = fmaf(ww.w, vx[d4 * 4 + 3], ax); ay = fmaf(ww.w, vy[d4 * 4 + 3], ay);
        }
        float2 r; r.x = ax; r.y = ay;
        *reinterpret_cast<float2*>(&ob[(size_t)c * HW + pixBase]) = r;
    }
}

// ---------------------------------------------------------------------------
extern "C" void kernel_launch(void* const* d_in, const int* in_sizes, int n_in,
                              void* d_out, int out_size, void* d_ws, size_t ws_size,
                              hipStream_t stream) {
    const float* fea0 = (const float*)d_in[0];
    const float* fea1 = (const float*)d_in[1];
    const float* qk_w = (const float*)d_in[2];
    const float* qk_dw = (const float*)d_in[3];
    const float* v_w = (const float*)d_in[4];
    const float* v_dw = (const float*)d_in[5];
    const float* proj_w = (const float*)d_in[6];
    const float* temperature = (const float*)d_in[7];
    float* out = (float*)d_out;

    char* ws = (char*)d_ws;
    const size_t V_BYTES = (size_t)NB * NC_IN * HW * sizeof(float);  // 50,331,648
    const size_t ST_BYTES = (size_t)NB * 384 * sizeof(float);
    float* v_buf = (float*)ws;
    float* stats = (float*)(ws + V_BYTES);
    float* w2 = (float*)(ws + V_BYTES + ST_BYTES);

    hipMemsetAsync(stats, 0, ST_BYTES, stream);

    fused_qk_stats_kernel<<<dim3(NTILES, NB), 256, 0, stream>>>(fea0, qk_w, qk_dw, stats);
    fused_v_kernel<<<dim3(NTILES, NB), 256, 0, stream>>>(fea1, v_w, v_dw, v_buf);
    softmax_w2_kernel<<<NB, 256, 0, stream>>>(stats, proj_w, temperature, w2);
    out_kernel<<<dim3(HW / 512, NB), 256, 0, stream>>>(v_buf, w2, out);
}